// Round 11
// baseline (312.306 us; speedup 1.0000x reference)
//
#include <hip/hip_runtime.h>
#include <hip/hip_bf16.h>

typedef __bf16 bf16;
typedef __attribute__((ext_vector_type(8))) __bf16 bf16x8;
typedef __attribute__((ext_vector_type(4))) float f32x4;

__device__ __forceinline__ void gload_lds16(const void* g, void* l) {
    __builtin_amdgcn_global_load_lds(
        (const __attribute__((address_space(1))) unsigned int*)g,
        (__attribute__((address_space(3))) unsigned int*)l, 16, 0, 0);
}

#define BARRIER()   asm volatile("s_barrier" ::: "memory")
#define WAITLGKM0() asm volatile("s_waitcnt lgkmcnt(0)" ::: "memory")
#define WAITVM4()   asm volatile("s_waitcnt vmcnt(4)" ::: "memory")
#define WAITVM0()   asm volatile("s_waitcnt vmcnt(0)" ::: "memory")
#define SCHED0()    __builtin_amdgcn_sched_barrier(0)

__device__ __forceinline__ unsigned int pack2(float a, float b) {
    bf16 x = (bf16)a, y = (bf16)b;
    unsigned short ux, uy;
    __builtin_memcpy(&ux, &x, 2); __builtin_memcpy(&uy, &y, 2);
    return (unsigned int)ux | ((unsigned int)uy << 16);
}

// ---------------- mega prep kernel: corr_g | corr_f | wf1 | wg1 | cvt_x | small ----------------
__global__ void prep_all(const float* __restrict__ x, bf16* __restrict__ xbf,
                         const float* __restrict__ fp, const float* __restrict__ mean,
                         const float* __restrict__ Wg1, const float* __restrict__ Wf1,
                         bf16* __restrict__ Wall,
                         float* __restrict__ corr_g, float* __restrict__ corr_f,
                         const float* __restrict__ Wg2, bf16* __restrict__ Wg2T,
                         const float* __restrict__ Wf2, bf16* __restrict__ Wf2T,
                         const float* __restrict__ Wgh, bf16* __restrict__ WghT)
{
    __shared__ float tile[32][33];
    const int b = blockIdx.x;
    const int t = threadIdx.x;

    if (b < 192) {
        // corr[c][s] = sum_r (1-sig(fp[c,r]))*mean[r]*W[r,s]
        const int isF = (b >= 64);
        const int bb  = isF ? b - 64 : b;
        const int nsb = isF ? 8 : 4;
        const int c   = bb / nsb;
        const int sblk = bb % nsb;
        const int S   = isF ? 512 : 256;
        const float* W = isF ? Wf1 : (Wg1 + (long)c * 2048 * 256);
        float* corr = isF ? corr_f : corr_g;
        const int sl = t & 63;
        const int s  = sblk * 64 + sl;
        const int w  = t >> 6;
        const float* fpc = fp + c * 2048;
        float acc = 0.f;
#pragma unroll 4
        for (int r = w; r < 2048; r += 4) {
            const float g = 1.f / (1.f + expf(-fpc[r]));
            acc = fmaf((1.f - g) * mean[r], W[(long)r * S + s], acc);
        }
        float* red = &tile[0][0];
        red[w * 64 + sl] = acc;
        __syncthreads();
        if (w == 0)
            corr[(long)c * S + s] = red[sl] + red[64 + sl] + red[128 + sl] + red[192 + sl];
        return;
    }
    if (b < 2240) {
        // wf1: Wall[z] rows 256-767 <- sig(fp[z]) * Wf1^T
        const int i = b - 192;
        const int s0 = (i & 15) * 32;
        const int r0 = ((i >> 4) & 63) * 32;
        const int zz = i >> 10;
        const int tx = t & 31, ty = t >> 5;
#pragma unroll
        for (int k = 0; k < 32; k += 8)
            tile[ty + k][tx] = Wf1[(long)(r0 + ty + k) * 512 + s0 + tx];
        __syncthreads();
#pragma unroll 1
        for (int j = 0; j < 8; ++j) {
            const int z = zz * 8 + j;
            bf16* out = Wall + (long)z * 768 * 2048 + (long)256 * 2048;
            const float gv = 1.f / (1.f + expf(-fp[z * 2048 + r0 + tx]));
#pragma unroll
            for (int k = 0; k < 32; k += 8)
                out[(long)(s0 + ty + k) * 2048 + r0 + tx] = (bf16)(gv * tile[tx][ty + k]);
        }
        return;
    }
    if (b < 10432) {
        // wg1: Wall[z] rows 0-255 <- sig(fp[z]) * Wg1[z]^T
        const int i = b - 2240;
        const int s0 = (i & 7) * 32;
        const int r0 = ((i >> 3) & 63) * 32;
        const int z  = i >> 9;
        const int tx = t & 31, ty = t >> 5;
        const float* in = Wg1 + (long)z * 2048 * 256;
        bf16* out = Wall + (long)z * 768 * 2048;
#pragma unroll
        for (int k = 0; k < 32; k += 8)
            tile[ty + k][tx] = in[(long)(r0 + ty + k) * 256 + s0 + tx];
        __syncthreads();
        const float gv = 1.f / (1.f + expf(-fp[z * 2048 + r0 + tx]));
#pragma unroll
        for (int k = 0; k < 32; k += 8)
            out[(long)(s0 + ty + k) * 2048 + r0 + tx] = (bf16)(gv * tile[tx][ty + k]);
        return;
    }
    if (b < 14528) {
        // cvt_x
        const long i = ((long)(b - 10432) * 256 + t) * 8;
        float4 v0 = *(const float4*)(x + i);
        float4 v1 = *(const float4*)(x + i + 4);
        bf16x8 o;
        o[0]=(bf16)v0.x; o[1]=(bf16)v0.y; o[2]=(bf16)v0.z; o[3]=(bf16)v0.w;
        o[4]=(bf16)v1.x; o[5]=(bf16)v1.y; o[6]=(bf16)v1.z; o[7]=(bf16)v1.w;
        *(bf16x8*)(xbf + i) = o;
        return;
    }
    {
        // small transposes
        const int i = b - 14528;
        const float* in; bf16* out; int R, bx, by;
        if (i < 512) {
            const int z = i >> 5, rem = i & 31;
            bx = rem & 3; by = rem >> 2; R = 256;
            in = Wg2 + (long)z * 256 * 128; out = Wg2T + (long)z * 128 * 256;
        } else if (i < 576) {
            const int rem = i - 512;
            bx = rem & 3; by = rem >> 2; R = 512;
            in = Wf2; out = Wf2T;
        } else {
            const int rem = i - 576;
            bx = rem & 3; by = rem >> 2; R = 1024;
            in = Wgh; out = WghT;
        }
        const int s0 = bx * 32, r0 = by * 32;
        const int tx = t & 31, ty = t >> 5;
#pragma unroll
        for (int k = 0; k < 32; k += 8)
            tile[ty + k][tx] = in[(long)(r0 + ty + k) * 128 + s0 + tx];
        __syncthreads();
#pragma unroll
        for (int k = 0; k < 32; k += 8)
            out[(long)(s0 + ty + k) * R + r0 + tx] = (bf16)tile[tx][ty + k];
    }
}

// ---------------- 256x256 8-phase bf16 GEMM (K=2048), merged h+hf, fused cm ----------------
// ny==0 blocks: compute h tile in LDS, then cm = h @ Wg2T[c]^T + bg2 directly (h never stored).
// ny in {1,2}: store hf.
__global__ __launch_bounds__(512, 2)
void gemm256(const bf16* __restrict__ A, const bf16* __restrict__ Wall,
             const float* __restrict__ bg1, const float* __restrict__ corr_g,
             const float* __restrict__ bf1, const float* __restrict__ corr_f,
             const bf16* __restrict__ Wg2T, const float* __restrict__ bg2,
             bf16* __restrict__ cm_out, bf16* __restrict__ hf_out)
{
    __shared__ __align__(16) bf16 lds[2][4][8192];  // [buf][A0,A1,B0,B1][128*64]

    // bijective XCD swizzle, c-major
    const int bid = blockIdx.x;                 // grid = 768
    const int swz = (bid & 7) * 96 + (bid >> 3);
    const int c   = swz / 48;
    const int rem = swz % 48;
    const int ny  = rem / 16;
    const int m0  = (rem % 16) * 256;

    const int t = threadIdx.x, lane = t & 63, w = t >> 6;
    const int wr = w >> 2, wc = w & 3;
    const bf16* Bc = Wall + (long)c * 768 * 2048;

    const int rr = lane >> 3;
    const int qq = (lane & 7) ^ rr;
    const bf16* pA0 = A  + (long)(m0 + w * 16 + rr) * 2048 + qq * 8;
    const bf16* pA1 = pA0 + 8 * 2048;
    const bf16* pB0 = Bc + (long)(ny * 256 + w * 16 + rr) * 2048 + qq * 8;
    const bf16* pB1 = pB0 + 8 * 2048;

    const int l15 = lane & 15;
    const int q0 = (((lane >> 4) ^ (lane & 7))) * 8;
    const int aoff0 = l15 * 64 + q0, aoff1 = aoff0 ^ 32;
    const int boff0 = ((wc & 1) * 64 + l15) * 64 + q0, boff1 = boff0 ^ 32;
    const int hb = 2 + (wc >> 1);

    f32x4 acc[8][4] = {};
    bf16x8 Ax[4][2], Ay[4][2], Bx[2][2], By[2][2];

#define STG(buf, half, P0, P1, e) do { \
    gload_lds16((P0) + (e), &lds[buf][half][w * 1024]); \
    gload_lds16((P1) + (e), &lds[buf][half][w * 1024 + 512]); } while (0)

#define RDA(dst, buf, mb) do { _Pragma("unroll") \
    for (int mm = 0; mm < 4; ++mm) { \
        dst[mm][0] = *(const bf16x8*)&lds[buf][wr][aoff0 + (mb + mm) * 1024]; \
        dst[mm][1] = *(const bf16x8*)&lds[buf][wr][aoff1 + (mb + mm) * 1024]; } } while (0)

#define RDB(dst, buf, nh) do { _Pragma("unroll") \
    for (int nn = 0; nn < 2; ++nn) { \
        dst[nn][0] = *(const bf16x8*)&lds[buf][hb][boff0 + (nh * 2 + nn) * 1024]; \
        dst[nn][1] = *(const bf16x8*)&lds[buf][hb][boff1 + (nh * 2 + nn) * 1024]; } } while (0)

#define MFMA16(mb, Af, Bf, nh) do { __builtin_amdgcn_s_setprio(1); _Pragma("unroll") \
    for (int kk = 0; kk < 2; ++kk) { _Pragma("unroll") \
      for (int mm = 0; mm < 4; ++mm) { _Pragma("unroll") \
        for (int nn = 0; nn < 2; ++nn) { \
            acc[mb + mm][nh * 2 + nn] = __builtin_amdgcn_mfma_f32_16x16x32_bf16( \
                Af[mm][kk], Bf[nn][kk], acc[mb + mm][nh * 2 + nn], 0, 0, 0); } } } \
    __builtin_amdgcn_s_setprio(0); } while (0)

    // prologue
    STG(0, 0, pA0, pA1, 0);
    STG(0, 1, pA0, pA1, 262144);
    STG(0, 2, pB0, pB1, 0);
    STG(0, 3, pB0, pB1, 262144);
    STG(1, 2, pB0, pB1, 64);
    STG(1, 3, pB0, pB1, 262144 + 64);
    WAITVM4();
    BARRIER();
    RDA(Ax, 0, 0); RDB(Bx, 0, 0);

#pragma unroll 1
    for (int it = 0; it < 15; ++it) {
        const int kB  = (2 * it + 1) * 64;
        const int kA2 = (2 * it + 2) * 64;
        const int kB2 = (2 * it + 3) * 64;
        // ph1
        STG(1, 0, pA0, pA1, kB);
        BARRIER();
        RDB(By, 0, 1);
        SCHED0();
        MFMA16(0, Ax, Bx, 0);
        BARRIER();
        // ph2
        STG(1, 1, pA0, pA1, 262144 + kB);
        BARRIER();
        RDA(Ay, 0, 4);
        SCHED0();
        MFMA16(0, Ax, By, 1);
        BARRIER();
        // ph3
        STG(0, 2, pB0, pB1, kA2);
        BARRIER();
        MFMA16(4, Ay, By, 1);
        BARRIER();
        // ph4
        STG(0, 3, pB0, pB1, 262144 + kA2);
        WAITVM4();
        BARRIER();
        RDA(Ax, 1, 0);
        SCHED0();
        MFMA16(4, Ay, Bx, 0);
        RDB(Bx, 1, 0);
        BARRIER();
        // ph5
        STG(0, 0, pA0, pA1, kA2);
        BARRIER();
        RDB(By, 1, 1);
        SCHED0();
        MFMA16(0, Ax, Bx, 0);
        BARRIER();
        // ph6
        STG(0, 1, pA0, pA1, 262144 + kA2);
        BARRIER();
        RDA(Ay, 1, 4);
        SCHED0();
        MFMA16(0, Ax, By, 1);
        BARRIER();
        // ph7
        STG(1, 2, pB0, pB1, kB2);
        BARRIER();
        MFMA16(4, Ay, By, 1);
        BARRIER();
        // ph8
        STG(1, 3, pB0, pB1, 262144 + kB2);
        WAITVM4();
        BARRIER();
        RDA(Ax, 0, 0);
        SCHED0();
        MFMA16(4, Ay, Bx, 0);
        RDB(Bx, 0, 0);
        BARRIER();
    }

    // ---- peeled it=15 ----
    {
        const int kB = 31 * 64;
        STG(1, 0, pA0, pA1, kB);
        BARRIER();
        RDB(By, 0, 1);
        SCHED0();
        MFMA16(0, Ax, Bx, 0);
        BARRIER();
        STG(1, 1, pA0, pA1, 262144 + kB);
        BARRIER();
        RDA(Ay, 0, 4);
        SCHED0();
        MFMA16(0, Ax, By, 1);
        BARRIER();
        MFMA16(4, Ay, By, 1);
        BARRIER();
        WAITVM0();
        BARRIER();
        RDA(Ax, 1, 0);
        SCHED0();
        MFMA16(4, Ay, Bx, 0);
        RDB(Bx, 1, 0);
        BARRIER();
        RDB(By, 1, 1);
        SCHED0();
        MFMA16(0, Ax, Bx, 0);
        BARRIER();
        RDA(Ay, 1, 4);
        SCHED0();
        MFMA16(0, Ax, By, 1);
        BARRIER();
        MFMA16(4, Ay, By, 1);
        MFMA16(4, Ay, Bx, 0);
    }

    // ---- epilogue: acc -> LDS bf16 [256][256], XOR-swizzled (row&7)<<4 ----
    WAITLGKM0();
    BARRIER();
    bf16* cst = (bf16*)&lds[0][0][0];
    const int r4 = (lane >> 4) * 4;
    const int isH = (ny == 0);
#pragma unroll
    for (int n = 0; n < 4; ++n) {
        const int cl = wc * 64 + n * 16 + l15;
        float bv;
        if (isH) bv = bg1[c * 256 + cl] + corr_g[c * 256 + cl];
        else {
            const int cf = (ny - 1) * 256 + cl;
            bv = bf1[cf] + corr_f[c * 512 + cf];
        }
#pragma unroll
        for (int m = 0; m < 8; ++m)
#pragma unroll
            for (int j = 0; j < 4; ++j) {
                const int row = wr * 128 + m * 16 + r4 + j;
                cst[row * 256 + (cl ^ ((row & 7) << 4))] = (bf16)fmaxf(acc[m][n][j] + bv, 0.0f);
            }
    }
    BARRIER();
    if (isH) {
        // fused cm: cm[m0+0..255][c*128+0..127] = cst(h) @ Wg2T[c]^T + bg2[c]
        const bf16* Wp = Wg2T + (long)c * 128 * 256;
        f32x4 a2[2][8] = {};
        const int rb = w * 32;   // wave's 32-row strip
#pragma unroll 1
        for (int ks = 0; ks < 8; ++ks) {
            bf16x8 af2[2], bqr[8];
            const int k0 = ks * 32 + (lane >> 4) * 8;
#pragma unroll
            for (int mt = 0; mt < 2; ++mt) {
                const int row = rb + mt * 16 + l15;
                af2[mt] = *(const bf16x8*)&cst[row * 256 + (k0 ^ ((row & 7) << 4))];
            }
#pragma unroll
            for (int nt = 0; nt < 8; ++nt)
                bqr[nt] = *(const bf16x8*)&Wp[(long)(nt * 16 + l15) * 256 + k0];
#pragma unroll
            for (int mt = 0; mt < 2; ++mt)
#pragma unroll
                for (int nt = 0; nt < 8; ++nt)
                    a2[mt][nt] = __builtin_amdgcn_mfma_f32_16x16x32_bf16(
                        af2[mt], bqr[nt], a2[mt][nt], 0, 0, 0);
        }
        bf16* cmp = cm_out + (long)(m0 + rb) * 2048 + c * 128;
#pragma unroll
        for (int mt = 0; mt < 2; ++mt)
#pragma unroll
            for (int nt = 0; nt < 8; ++nt) {
                const int col = nt * 16 + l15;
                const float bv2 = bg2[c * 128 + col];
#pragma unroll
                for (int j = 0; j < 4; ++j) {
                    const int row = mt * 16 + r4 + j;
                    cmp[(long)row * 2048 + col] = (bf16)(a2[mt][nt][j] + bv2);
                }
            }
    } else {
        bf16* obase = hf_out + ((long)c * 4096 + m0) * 512 + (ny - 1) * 256;
        const int trow = t >> 5, tch = (t & 31) * 8;
#pragma unroll
        for (int pass = 0; pass < 16; ++pass) {
            const int row = pass * 16 + trow;
            *(bf16x8*)&obase[(long)row * 512 + tch] =
                *(const bf16x8*)&cst[row * 256 + (tch ^ ((row & 7) << 4))];
        }
    }
#undef STG
#undef RDA
#undef RDB
#undef MFMA16
}

// ---------------- lat GEMM: lat[b][c][l] = hf[c] @ Wf2^T + bf2 ----------------
__global__ __launch_bounds__(256, 2)
void gemm_lat(const bf16* __restrict__ hf, const bf16* __restrict__ Wf2T,
              const float* __restrict__ bf2, bf16* __restrict__ lat)
{
    __shared__ __align__(16) bf16 As[128 * 64];
    __shared__ __align__(16) bf16 Bs[128 * 64];

    const int cidx = blockIdx.z;
    const int m0 = blockIdx.x * 128;
    const int t  = threadIdx.x;
    const int lane = t & 63, wave = t >> 6;
    const int wr = wave >> 1, wc = wave & 1;

    const bf16* Ac = hf + (long)cidx * 4096 * 512;
    bf16* outp = lat + (long)m0 * 2048 + cidx * 128;

    const int sr = t >> 3;
    const int sc = (t & 7) * 8;

    f32x4 acc[4][4] = {};

    for (int kt = 0; kt < 8; ++kt) {
        const int k0 = kt * 64;
#pragma unroll
        for (int i = 0; i < 4; ++i)
            gload_lds16(Ac + (long)(m0 + i * 32 + sr) * 512 + k0 + sc, &As[i * 2048 + wave * 512]);
#pragma unroll
        for (int i = 0; i < 4; ++i)
            gload_lds16(Wf2T + (long)(i * 32 + sr) * 512 + k0 + sc, &Bs[i * 2048 + wave * 512]);
        __syncthreads();

#pragma unroll
        for (int kk = 0; kk < 2; ++kk) {
            bf16x8 af[4], bfr[4];
#pragma unroll
            for (int m = 0; m < 4; ++m)
                af[m] = *(const bf16x8*)&As[(wr * 64 + m * 16 + (lane & 15)) * 64 + kk * 32 + (lane >> 4) * 8];
#pragma unroll
            for (int n = 0; n < 4; ++n)
                bfr[n] = *(const bf16x8*)&Bs[(wc * 64 + n * 16 + (lane & 15)) * 64 + kk * 32 + (lane >> 4) * 8];
#pragma unroll
            for (int m = 0; m < 4; ++m)
#pragma unroll
                for (int n = 0; n < 4; ++n)
                    acc[m][n] = __builtin_amdgcn_mfma_f32_16x16x32_bf16(af[m], bfr[n], acc[m][n], 0, 0, 0);
        }
        __syncthreads();
    }

    const int ci = lane & 15, r4 = (lane >> 4) * 4;
#pragma unroll
    for (int m = 0; m < 4; ++m)
#pragma unroll
        for (int n = 0; n < 4; ++n) {
            const int col = wc * 64 + n * 16 + ci;
            const float bv = bf2[col];
#pragma unroll
            for (int j = 0; j < 4; ++j) {
                const int row = wr * 64 + m * 16 + r4 + j;
                outp[(long)row * 2048 + col] = (bf16)(acc[m][n][j] + bv);
            }
        }
}

// ---------------- zp GEMM: split-K=8 partials (bf16 out) ----------------
__global__ __launch_bounds__(256, 2)
void gemm_zp(const bf16* __restrict__ A, const bf16* __restrict__ Wt,
             bf16* __restrict__ outb)
{
    __shared__ __align__(16) bf16 As[128 * 64];
    __shared__ __align__(16) bf16 Bs[128 * 64];

    const int z  = blockIdx.z;
    const int m0 = blockIdx.x * 128;
    const int t  = threadIdx.x;
    const int lane = t & 63, wave = t >> 6;
    const int wr = wave >> 1, wc = wave & 1;

    const bf16* Ac = A  + (long)z * 128;
    const bf16* W  = Wt + (long)z * 128;
    bf16* outp = outb + (long)z * 4096 * 128 + (long)m0 * 128;

    const int sr = t >> 3;
    const int sc = (t & 7) * 8;

    f32x4 acc[4][4] = {};

    for (int kt = 0; kt < 2; ++kt) {
        const int k0 = kt * 64;
#pragma unroll
        for (int i = 0; i < 4; ++i)
            gload_lds16(Ac + (long)(m0 + i * 32 + sr) * 1024 + k0 + sc, &As[i * 2048 + wave * 512]);
#pragma unroll
        for (int i = 0; i < 4; ++i)
            gload_lds16(W + (long)(i * 32 + sr) * 1024 + k0 + sc, &Bs[i * 2048 + wave * 512]);
        __syncthreads();

#pragma unroll
        for (int kk = 0; kk < 2; ++kk) {
            bf16x8 af[4], bfr[4];
#pragma unroll
            for (int m = 0; m < 4; ++m)
                af[m] = *(const bf16x8*)&As[(wr * 64 + m * 16 + (lane & 15)) * 64 + kk * 32 + (lane >> 4) * 8];
#pragma unroll
            for (int n = 0; n < 4; ++n)
                bfr[n] = *(const bf16x8*)&Bs[(wc * 64 + n * 16 + (lane & 15)) * 64 + kk * 32 + (lane >> 4) * 8];
#pragma unroll
            for (int m = 0; m < 4; ++m)
#pragma unroll
                for (int n = 0; n < 4; ++n)
                    acc[m][n] = __builtin_amdgcn_mfma_f32_16x16x32_bf16(af[m], bfr[n], acc[m][n], 0, 0, 0);
        }
        __syncthreads();
    }

    const int ci = lane & 15, r4 = (lane >> 4) * 4;
#pragma unroll
    for (int m = 0; m < 4; ++m)
#pragma unroll
        for (int n = 0; n < 4; ++n) {
            const int col = wc * 64 + n * 16 + ci;
#pragma unroll
            for (int j = 0; j < 4; ++j) {
                const int row = wr * 64 + m * 16 + r4 + j;
                outp[(long)row * 128 + col] = (bf16)acc[m][n][j];
            }
        }
}

// ---------------- fusion (vectorized) ----------------
__global__ void fuse_kernel(const unsigned int* __restrict__ cm, const unsigned int* __restrict__ lat,
                            unsigned int* __restrict__ bott)
{
    const int wave = threadIdx.x >> 6;
    const int l    = threadIdx.x & 63;
    const int b    = blockIdx.x * 4 + wave;
    const unsigned int* cu = cm  + (size_t)b * 1024;
    const unsigned int* lu = lat + (size_t)b * 1024;

    float c0[16], c1[16], l0[16], l1[16];
    float sq0 = 0.f, sq1 = 0.f;
#pragma unroll
    for (int c = 0; c < 16; ++c) {
        const unsigned int vc = cu[c * 64 + l], vl = lu[c * 64 + l];
        c0[c] = __uint_as_float(vc << 16);
        c1[c] = __uint_as_float(vc & 0xffff0000u);
        l0[c] = __uint_as_float(vl << 16);
        l1[c] = __uint_as_float(vl & 0xffff0000u);
        sq0 += c0[c] * c0[c]; sq1 += c1[c] * c1[c];
    }
    const float rs0 = rsqrtf(fmaxf(sq0, 1e-12f));
    const float rs1 = rsqrtf(fmaxf(sq1, 1e-12f));
#pragma unroll
    for (int c = 0; c < 16; ++c) {
        const float cn0 = c0[c] * rs0, cn1 = c1[c] * rs1;
        float part = cn0 * l0[c] + cn1 * l1[c];
#pragma unroll
        for (int off = 32; off; off >>= 1) part += __shfl_xor(part, off);
        const float p = 1.0f / (1.0f + expf(-part));
        const float o0 = __shfl_xor(cn0, 32), o1 = __shfl_xor(cn1, 32);
        if (l < 32)
            bott[(size_t)b * 512 + c * 32 + l] =
                pack2(p * o0 + (1.f - p) * cn0, p * o1 + (1.f - p) * cn1);
    }
}

// ---------------- final: reduce z partials (bf16), relu, logits ----------------
__global__ void head2_kernel(const bf16* __restrict__ zp, const float* __restrict__ bgh,
                             const float* __restrict__ Wc, const float* __restrict__ bc,
                             float* __restrict__ out)
{
    __shared__ float zs[8][128];
    const int b0 = blockIdx.x * 8;
    const int t = threadIdx.x;
#pragma unroll
    for (int i = 0; i < 4; ++i) {
        const int idx = t + i * 256;
        const int r = idx >> 7, k = idx & 127;
        float s = bgh[k];
#pragma unroll
        for (int ks = 0; ks < 8; ++ks)
            s += (float)zp[(size_t)ks * 524288 + (size_t)(b0 + r) * 128 + k];
        zs[r][k] = fmaxf(s, 0.0f);
    }
    __syncthreads();
    if (t < 200) {
        float a[8];
#pragma unroll
        for (int r = 0; r < 8; ++r) a[r] = bc[t];
        for (int k = 0; k < 128; ++k) {
            const float wv = Wc[k * 200 + t];
#pragma unroll
            for (int r = 0; r < 8; ++r) a[r] = fmaf(zs[r][k], wv, a[r]);
        }
#pragma unroll
        for (int r = 0; r < 8; ++r) out[(size_t)(b0 + r) * 200 + t] = a[r];
    }
}

// ---------------- launch ----------------

extern "C" void kernel_launch(void* const* d_in, const int* in_sizes, int n_in,
                              void* d_out, int out_size, void* d_ws, size_t ws_size,
                              hipStream_t stream)
{
    (void)in_sizes; (void)n_in; (void)out_size; (void)ws_size;

    const float* x    = (const float*)d_in[0];
    const float* fp   = (const float*)d_in[1];
    const float* mean = (const float*)d_in[2];
    const float* Wg1  = (const float*)d_in[3];
    const float* bg1  = (const float*)d_in[4];
    const float* Wg2  = (const float*)d_in[5];
    const float* bg2  = (const float*)d_in[6];
    const float* Wf1  = (const float*)d_in[7];
    const float* bf1  = (const float*)d_in[8];
    const float* Wf2  = (const float*)d_in[9];
    const float* bf2  = (const float*)d_in[10];
    const float* Wgh  = (const float*)d_in[11];
    const float* bgh  = (const float*)d_in[12];
    const float* Wc   = (const float*)d_in[13];
    const float* bc   = (const float*)d_in[14];
    float* outp = (float*)d_out;

    char* p = (char*)d_ws;
    size_t off = 0;
    auto alloc = [&](size_t bytes) { void* r = p + off; off += (bytes + 255) & ~(size_t)255; return r; };
    bf16*  xbf    = (bf16*) alloc((size_t)4096 * 2048 * 2);
    bf16*  Wall   = (bf16*) alloc((size_t)16 * 768 * 2048 * 2);
    bf16*  Wg2T   = (bf16*) alloc((size_t)16 * 128 * 256 * 2);
    bf16*  Wf2T   = (bf16*) alloc((size_t)128 * 512 * 2);
    bf16*  WghT   = (bf16*) alloc((size_t)128 * 1024 * 2);
    float* corr_g = (float*)alloc((size_t)16 * 256 * 4);
    float* corr_f = (float*)alloc((size_t)16 * 512 * 4);
    bf16*  hf     = (bf16*) alloc((size_t)16 * 4096 * 512 * 2);
    bf16*  cm     = (bf16*) alloc((size_t)4096 * 2048 * 2);
    bf16*  lat    = (bf16*) alloc((size_t)4096 * 2048 * 2);
    bf16*  bott   = (bf16*) alloc((size_t)4096 * 1024 * 2);
    bf16*  zp     = (bf16*) alloc((size_t)8 * 4096 * 128 * 2);

    prep_all<<<15232, 256, 0, stream>>>(x, xbf, fp, mean, Wg1, Wf1, Wall,
                                        corr_g, corr_f, Wg2, Wg2T, Wf2, Wf2T, Wgh, WghT);

    gemm256<<<768, 512, 0, stream>>>(xbf, Wall, bg1, corr_g, bf1, corr_f,
                                     Wg2T, bg2, cm, hf);

    gemm_lat<<<dim3(32, 1, 16), 256, 0, stream>>>(hf, Wf2T, bf2, lat);

    fuse_kernel<<<1024, 256, 0, stream>>>((const unsigned int*)cm, (const unsigned int*)lat,
                                          (unsigned int*)bott);

    gemm_zp<<<dim3(32, 1, 8), 256, 0, stream>>>(bott, WghT, zp);

    head2_kernel<<<512, 256, 0, stream>>>(zp, bgh, Wc, bc, outp);
}

// Round 12
// 307.284 us; speedup vs baseline: 1.0163x; 1.0163x over previous
//
#include <hip/hip_runtime.h>
#include <hip/hip_bf16.h>

typedef __bf16 bf16;
typedef __attribute__((ext_vector_type(8))) __bf16 bf16x8;
typedef __attribute__((ext_vector_type(4))) float f32x4;

__device__ __forceinline__ void gload_lds16(const void* g, void* l) {
    __builtin_amdgcn_global_load_lds(
        (const __attribute__((address_space(1))) unsigned int*)g,
        (__attribute__((address_space(3))) unsigned int*)l, 16, 0, 0);
}

#define BARRIER()   asm volatile("s_barrier" ::: "memory")
#define WAITLGKM0() asm volatile("s_waitcnt lgkmcnt(0)" ::: "memory")
#define WAITVM4()   asm volatile("s_waitcnt vmcnt(4)" ::: "memory")
#define WAITVM0()   asm volatile("s_waitcnt vmcnt(0)" ::: "memory")
#define SCHED0()    __builtin_amdgcn_sched_barrier(0)

__device__ __forceinline__ unsigned int pack2(float a, float b) {
    bf16 x = (bf16)a, y = (bf16)b;
    unsigned short ux, uy;
    __builtin_memcpy(&ux, &x, 2); __builtin_memcpy(&uy, &y, 2);
    return (unsigned int)ux | ((unsigned int)uy << 16);
}

// ---------------- mega prep kernel: corr_g | corr_f | wf1 | wg1 | cvt_x | small ----------------
// block ranges:
//   [0,64)            corr_g   (4 s-blocks x 16 c)
//   [64,192)          corr_f   (8 s-blocks x 16 c)
//   [192,2240)        wf1      (16 x, 64 y, 2 zz; 8-z inner loop)
//   [2240,10432)      wg1      (8 x, 64 y, 16 z)
//   [10432,14528)     cvt_x    (4096)
//   [14528,15232)     small    (704)
__global__ void prep_all(const float* __restrict__ x, bf16* __restrict__ xbf,
                         const float* __restrict__ fp, const float* __restrict__ mean,
                         const float* __restrict__ Wg1, const float* __restrict__ Wf1,
                         bf16* __restrict__ Wall,
                         float* __restrict__ corr_g, float* __restrict__ corr_f,
                         const float* __restrict__ Wg2, bf16* __restrict__ Wg2T,
                         const float* __restrict__ Wf2, bf16* __restrict__ Wf2T,
                         const float* __restrict__ Wgh, bf16* __restrict__ WghT)
{
    __shared__ float tile[32][33];
    const int b = blockIdx.x;
    const int t = threadIdx.x;

    if (b < 192) {
        // corr[c][s] = sum_r (1-sig(fp[c,r]))*mean[r]*W[r,s]
        const int isF = (b >= 64);
        const int bb  = isF ? b - 64 : b;
        const int nsb = isF ? 8 : 4;
        const int c   = bb / nsb;
        const int sblk = bb % nsb;
        const int S   = isF ? 512 : 256;
        const float* W = isF ? Wf1 : (Wg1 + (long)c * 2048 * 256);
        float* corr = isF ? corr_f : corr_g;
        const int sl = t & 63;
        const int s  = sblk * 64 + sl;
        const int w  = t >> 6;
        const float* fpc = fp + c * 2048;
        float acc = 0.f;
#pragma unroll 4
        for (int r = w; r < 2048; r += 4) {
            const float g = 1.f / (1.f + expf(-fpc[r]));
            acc = fmaf((1.f - g) * mean[r], W[(long)r * S + s], acc);
        }
        float* red = &tile[0][0];
        red[w * 64 + sl] = acc;
        __syncthreads();
        if (w == 0)
            corr[(long)c * S + s] = red[sl] + red[64 + sl] + red[128 + sl] + red[192 + sl];
        return;
    }
    if (b < 2240) {
        // wf1: Wall[z] rows 256-767 <- sig(fp[z]) * Wf1^T
        const int i = b - 192;
        const int s0 = (i & 15) * 32;
        const int r0 = ((i >> 4) & 63) * 32;
        const int zz = i >> 10;
        const int tx = t & 31, ty = t >> 5;
#pragma unroll
        for (int k = 0; k < 32; k += 8)
            tile[ty + k][tx] = Wf1[(long)(r0 + ty + k) * 512 + s0 + tx];
        __syncthreads();
#pragma unroll 1
        for (int j = 0; j < 8; ++j) {
            const int z = zz * 8 + j;
            bf16* out = Wall + (long)z * 768 * 2048 + (long)256 * 2048;
            const float gv = 1.f / (1.f + expf(-fp[z * 2048 + r0 + tx]));
#pragma unroll
            for (int k = 0; k < 32; k += 8)
                out[(long)(s0 + ty + k) * 2048 + r0 + tx] = (bf16)(gv * tile[tx][ty + k]);
        }
        return;
    }
    if (b < 10432) {
        // wg1: Wall[z] rows 0-255 <- sig(fp[z]) * Wg1[z]^T
        const int i = b - 2240;
        const int s0 = (i & 7) * 32;
        const int r0 = ((i >> 3) & 63) * 32;
        const int z  = i >> 9;
        const int tx = t & 31, ty = t >> 5;
        const float* in = Wg1 + (long)z * 2048 * 256;
        bf16* out = Wall + (long)z * 768 * 2048;
#pragma unroll
        for (int k = 0; k < 32; k += 8)
            tile[ty + k][tx] = in[(long)(r0 + ty + k) * 256 + s0 + tx];
        __syncthreads();
        const float gv = 1.f / (1.f + expf(-fp[z * 2048 + r0 + tx]));
#pragma unroll
        for (int k = 0; k < 32; k += 8)
            out[(long)(s0 + ty + k) * 2048 + r0 + tx] = (bf16)(gv * tile[tx][ty + k]);
        return;
    }
    if (b < 14528) {
        // cvt_x
        const long i = ((long)(b - 10432) * 256 + t) * 8;
        float4 v0 = *(const float4*)(x + i);
        float4 v1 = *(const float4*)(x + i + 4);
        bf16x8 o;
        o[0]=(bf16)v0.x; o[1]=(bf16)v0.y; o[2]=(bf16)v0.z; o[3]=(bf16)v0.w;
        o[4]=(bf16)v1.x; o[5]=(bf16)v1.y; o[6]=(bf16)v1.z; o[7]=(bf16)v1.w;
        *(bf16x8*)(xbf + i) = o;
        return;
    }
    {
        // small transposes
        const int i = b - 14528;
        const float* in; bf16* out; int R, bx, by;
        if (i < 512) {
            const int z = i >> 5, rem = i & 31;
            bx = rem & 3; by = rem >> 2; R = 256;
            in = Wg2 + (long)z * 256 * 128; out = Wg2T + (long)z * 128 * 256;
        } else if (i < 576) {
            const int rem = i - 512;
            bx = rem & 3; by = rem >> 2; R = 512;
            in = Wf2; out = Wf2T;
        } else {
            const int rem = i - 576;
            bx = rem & 3; by = rem >> 2; R = 1024;
            in = Wgh; out = WghT;
        }
        const int s0 = bx * 32, r0 = by * 32;
        const int tx = t & 31, ty = t >> 5;
#pragma unroll
        for (int k = 0; k < 32; k += 8)
            tile[ty + k][tx] = in[(long)(r0 + ty + k) * 128 + s0 + tx];
        __syncthreads();
#pragma unroll
        for (int k = 0; k < 32; k += 8)
            out[(long)(s0 + ty + k) * R + r0 + tx] = (bf16)tile[tx][ty + k];
    }
}

// ---------------- 256x256 8-phase bf16 GEMM (K=2048), merged h+hf ----------------
__global__ __launch_bounds__(512, 2)
void gemm256(const bf16* __restrict__ A, const bf16* __restrict__ Wall,
             const float* __restrict__ bg1, const float* __restrict__ corr_g,
             const float* __restrict__ bf1, const float* __restrict__ corr_f,
             bf16* __restrict__ h_out, bf16* __restrict__ hf_out)
{
    __shared__ __align__(16) bf16 lds[2][4][8192];  // [buf][A0,A1,B0,B1][128*64]

    // bijective XCD swizzle, c-major
    const int bid = blockIdx.x;                 // grid = 768
    const int swz = (bid & 7) * 96 + (bid >> 3);
    const int c   = swz / 48;
    const int rem = swz % 48;
    const int ny  = rem / 16;
    const int m0  = (rem % 16) * 256;

    const int t = threadIdx.x, lane = t & 63, w = t >> 6;
    const int wr = w >> 2, wc = w & 3;
    const bf16* Bc = Wall + (long)c * 768 * 2048;

    const int rr = lane >> 3;
    const int qq = (lane & 7) ^ rr;
    const bf16* pA0 = A  + (long)(m0 + w * 16 + rr) * 2048 + qq * 8;
    const bf16* pA1 = pA0 + 8 * 2048;
    const bf16* pB0 = Bc + (long)(ny * 256 + w * 16 + rr) * 2048 + qq * 8;
    const bf16* pB1 = pB0 + 8 * 2048;

    const int l15 = lane & 15;
    const int q0 = (((lane >> 4) ^ (lane & 7))) * 8;
    const int aoff0 = l15 * 64 + q0, aoff1 = aoff0 ^ 32;
    const int boff0 = ((wc & 1) * 64 + l15) * 64 + q0, boff1 = boff0 ^ 32;
    const int hb = 2 + (wc >> 1);

    f32x4 acc[8][4] = {};
    bf16x8 Ax[4][2], Ay[4][2], Bx[2][2], By[2][2];

#define STG(buf, half, P0, P1, e) do { \
    gload_lds16((P0) + (e), &lds[buf][half][w * 1024]); \
    gload_lds16((P1) + (e), &lds[buf][half][w * 1024 + 512]); } while (0)

#define RDA(dst, buf, mb) do { _Pragma("unroll") \
    for (int mm = 0; mm < 4; ++mm) { \
        dst[mm][0] = *(const bf16x8*)&lds[buf][wr][aoff0 + (mb + mm) * 1024]; \
        dst[mm][1] = *(const bf16x8*)&lds[buf][wr][aoff1 + (mb + mm) * 1024]; } } while (0)

#define RDB(dst, buf, nh) do { _Pragma("unroll") \
    for (int nn = 0; nn < 2; ++nn) { \
        dst[nn][0] = *(const bf16x8*)&lds[buf][hb][boff0 + (nh * 2 + nn) * 1024]; \
        dst[nn][1] = *(const bf16x8*)&lds[buf][hb][boff1 + (nh * 2 + nn) * 1024]; } } while (0)

#define MFMA16(mb, Af, Bf, nh) do { __builtin_amdgcn_s_setprio(1); _Pragma("unroll") \
    for (int kk = 0; kk < 2; ++kk) { _Pragma("unroll") \
      for (int mm = 0; mm < 4; ++mm) { _Pragma("unroll") \
        for (int nn = 0; nn < 2; ++nn) { \
            acc[mb + mm][nh * 2 + nn] = __builtin_amdgcn_mfma_f32_16x16x32_bf16( \
                Af[mm][kk], Bf[nn][kk], acc[mb + mm][nh * 2 + nn], 0, 0, 0); } } } \
    __builtin_amdgcn_s_setprio(0); } while (0)

    // prologue
    STG(0, 0, pA0, pA1, 0);
    STG(0, 1, pA0, pA1, 262144);
    STG(0, 2, pB0, pB1, 0);
    STG(0, 3, pB0, pB1, 262144);
    STG(1, 2, pB0, pB1, 64);
    STG(1, 3, pB0, pB1, 262144 + 64);
    WAITVM4();
    BARRIER();
    RDA(Ax, 0, 0); RDB(Bx, 0, 0);

#pragma unroll 1
    for (int it = 0; it < 15; ++it) {
        const int kB  = (2 * it + 1) * 64;
        const int kA2 = (2 * it + 2) * 64;
        const int kB2 = (2 * it + 3) * 64;
        // ph1
        STG(1, 0, pA0, pA1, kB);
        BARRIER();
        RDB(By, 0, 1);
        SCHED0();
        MFMA16(0, Ax, Bx, 0);
        BARRIER();
        // ph2
        STG(1, 1, pA0, pA1, 262144 + kB);
        BARRIER();
        RDA(Ay, 0, 4);
        SCHED0();
        MFMA16(0, Ax, By, 1);
        BARRIER();
        // ph3
        STG(0, 2, pB0, pB1, kA2);
        BARRIER();
        MFMA16(4, Ay, By, 1);
        BARRIER();
        // ph4
        STG(0, 3, pB0, pB1, 262144 + kA2);
        WAITVM4();
        BARRIER();
        RDA(Ax, 1, 0);
        SCHED0();
        MFMA16(4, Ay, Bx, 0);
        RDB(Bx, 1, 0);
        BARRIER();
        // ph5
        STG(0, 0, pA0, pA1, kA2);
        BARRIER();
        RDB(By, 1, 1);
        SCHED0();
        MFMA16(0, Ax, Bx, 0);
        BARRIER();
        // ph6
        STG(0, 1, pA0, pA1, 262144 + kA2);
        BARRIER();
        RDA(Ay, 1, 4);
        SCHED0();
        MFMA16(0, Ax, By, 1);
        BARRIER();
        // ph7
        STG(1, 2, pB0, pB1, kB2);
        BARRIER();
        MFMA16(4, Ay, By, 1);
        BARRIER();
        // ph8
        STG(1, 3, pB0, pB1, 262144 + kB2);
        WAITVM4();
        BARRIER();
        RDA(Ax, 0, 0);
        SCHED0();
        MFMA16(4, Ay, Bx, 0);
        RDB(Bx, 0, 0);
        BARRIER();
    }

    // ---- peeled it=15 ----
    {
        const int kB = 31 * 64;
        STG(1, 0, pA0, pA1, kB);
        BARRIER();
        RDB(By, 0, 1);
        SCHED0();
        MFMA16(0, Ax, Bx, 0);
        BARRIER();
        STG(1, 1, pA0, pA1, 262144 + kB);
        BARRIER();
        RDA(Ay, 0, 4);
        SCHED0();
        MFMA16(0, Ax, By, 1);
        BARRIER();
        MFMA16(4, Ay, By, 1);
        BARRIER();
        WAITVM0();
        BARRIER();
        RDA(Ax, 1, 0);
        SCHED0();
        MFMA16(4, Ay, Bx, 0);
        RDB(Bx, 1, 0);
        BARRIER();
        RDB(By, 1, 1);
        SCHED0();
        MFMA16(0, Ax, Bx, 0);
        BARRIER();
        RDA(Ay, 1, 4);
        SCHED0();
        MFMA16(0, Ax, By, 1);
        BARRIER();
        MFMA16(4, Ay, By, 1);
        MFMA16(4, Ay, Bx, 0);
    }

    // ---- epilogue: acc -> LDS bf16 [256][256] -> coalesced stores ----
    WAITLGKM0();
    BARRIER();
    bf16* cst = (bf16*)&lds[0][0][0];
    const int r4 = (lane >> 4) * 4;
    const int isH = (ny == 0);
    const int N = isH ? 256 : 512;
#pragma unroll
    for (int n = 0; n < 4; ++n) {
        const int cl = wc * 64 + n * 16 + l15;
        float bv;
        if (isH) bv = bg1[c * 256 + cl] + corr_g[c * 256 + cl];
        else {
            const int cf = (ny - 1) * 256 + cl;
            bv = bf1[cf] + corr_f[c * 512 + cf];
        }
#pragma unroll
        for (int m = 0; m < 8; ++m)
#pragma unroll
            for (int j = 0; j < 4; ++j) {
                const int row = wr * 128 + m * 16 + r4 + j;
                cst[row * 256 + cl] = (bf16)fmaxf(acc[m][n][j] + bv, 0.0f);
            }
    }
    BARRIER();
    bf16* obase = isH ? h_out + ((long)c * 4096 + m0) * 256
                      : hf_out + ((long)c * 4096 + m0) * 512 + (ny - 1) * 256;
    const int trow = t >> 5, tch = (t & 31) * 8;
#pragma unroll
    for (int pass = 0; pass < 16; ++pass) {
        const int row = pass * 16 + trow;
        *(bf16x8*)&obase[(long)row * N + tch] = *(const bf16x8*)&cst[row * 256 + tch];
    }
#undef STG
#undef RDA
#undef RDB
#undef MFMA16
}

// ---------------- merged mid GEMMs: cm (z<16, K=256) and lat (z>=16, K=512) ----------------
__global__ __launch_bounds__(256, 2)
void gemm_mid(const bf16* __restrict__ h, const bf16* __restrict__ hf,
              const bf16* __restrict__ Wg2T, const bf16* __restrict__ Wf2T,
              const float* __restrict__ bg2, const float* __restrict__ bf2,
              bf16* __restrict__ cm, bf16* __restrict__ lat)
{
    __shared__ __align__(16) bf16 As[128 * 64];
    __shared__ __align__(16) bf16 Bs[128 * 64];

    const int z  = blockIdx.z;
    const int m0 = blockIdx.x * 128;
    const int t  = threadIdx.x;
    const int lane = t & 63, wave = t >> 6;
    const int wr = wave >> 1, wc = wave & 1;

    int K; const bf16 *Ac, *W; const float* bias; bf16* outp;
    if (z < 16) {
        K = 256; Ac = h + (long)z * 4096 * 256; W = Wg2T + (long)z * 128 * 256;
        bias = bg2 + z * 128; outp = cm + (long)m0 * 2048 + z * 128;
    } else {
        const int c = z - 16;
        K = 512; Ac = hf + (long)c * 4096 * 512; W = Wf2T;
        bias = bf2; outp = lat + (long)m0 * 2048 + c * 128;
    }

    const int sr = t >> 3;
    const int sc = (t & 7) * 8;

    f32x4 acc[4][4] = {};

    for (int kt = 0; kt < K / 64; ++kt) {
        const int k0 = kt * 64;
#pragma unroll
        for (int i = 0; i < 4; ++i)
            gload_lds16(Ac + (long)(m0 + i * 32 + sr) * K + k0 + sc, &As[i * 2048 + wave * 512]);
#pragma unroll
        for (int i = 0; i < 4; ++i)
            gload_lds16(W + (long)(i * 32 + sr) * K + k0 + sc, &Bs[i * 2048 + wave * 512]);
        __syncthreads();

#pragma unroll
        for (int kk = 0; kk < 2; ++kk) {
            bf16x8 af[4], bfr[4];
#pragma unroll
            for (int m = 0; m < 4; ++m)
                af[m] = *(const bf16x8*)&As[(wr * 64 + m * 16 + (lane & 15)) * 64 + kk * 32 + (lane >> 4) * 8];
#pragma unroll
            for (int n = 0; n < 4; ++n)
                bfr[n] = *(const bf16x8*)&Bs[(wc * 64 + n * 16 + (lane & 15)) * 64 + kk * 32 + (lane >> 4) * 8];
#pragma unroll
            for (int m = 0; m < 4; ++m)
#pragma unroll
                for (int n = 0; n < 4; ++n)
                    acc[m][n] = __builtin_amdgcn_mfma_f32_16x16x32_bf16(af[m], bfr[n], acc[m][n], 0, 0, 0);
        }
        __syncthreads();
    }

    const int ci = lane & 15, r4 = (lane >> 4) * 4;
#pragma unroll
    for (int m = 0; m < 4; ++m)
#pragma unroll
        for (int n = 0; n < 4; ++n) {
            const int col = wc * 64 + n * 16 + ci;
            const float bv = bias[col];
#pragma unroll
            for (int j = 0; j < 4; ++j) {
                const int row = wr * 64 + m * 16 + r4 + j;
                outp[(long)row * 2048 + col] = (bf16)(acc[m][n][j] + bv);
            }
        }
}

// ---------------- zp GEMM: split-K=8 partials (bf16 out) ----------------
__global__ __launch_bounds__(256, 2)
void gemm_zp(const bf16* __restrict__ A, const bf16* __restrict__ Wt,
             bf16* __restrict__ outb)
{
    __shared__ __align__(16) bf16 As[128 * 64];
    __shared__ __align__(16) bf16 Bs[128 * 64];

    const int z  = blockIdx.z;
    const int m0 = blockIdx.x * 128;
    const int t  = threadIdx.x;
    const int lane = t & 63, wave = t >> 6;
    const int wr = wave >> 1, wc = wave & 1;

    const bf16* Ac = A  + (long)z * 128;
    const bf16* W  = Wt + (long)z * 128;
    bf16* outp = outb + (long)z * 4096 * 128 + (long)m0 * 128;

    const int sr = t >> 3;
    const int sc = (t & 7) * 8;

    f32x4 acc[4][4] = {};

    for (int kt = 0; kt < 2; ++kt) {
        const int k0 = kt * 64;
#pragma unroll
        for (int i = 0; i < 4; ++i)
            gload_lds16(Ac + (long)(m0 + i * 32 + sr) * 1024 + k0 + sc, &As[i * 2048 + wave * 512]);
#pragma unroll
        for (int i = 0; i < 4; ++i)
            gload_lds16(W + (long)(i * 32 + sr) * 1024 + k0 + sc, &Bs[i * 2048 + wave * 512]);
        __syncthreads();

#pragma unroll
        for (int kk = 0; kk < 2; ++kk) {
            bf16x8 af[4], bfr[4];
#pragma unroll
            for (int m = 0; m < 4; ++m)
                af[m] = *(const bf16x8*)&As[(wr * 64 + m * 16 + (lane & 15)) * 64 + kk * 32 + (lane >> 4) * 8];
#pragma unroll
            for (int n = 0; n < 4; ++n)
                bfr[n] = *(const bf16x8*)&Bs[(wc * 64 + n * 16 + (lane & 15)) * 64 + kk * 32 + (lane >> 4) * 8];
#pragma unroll
            for (int m = 0; m < 4; ++m)
#pragma unroll
                for (int n = 0; n < 4; ++n)
                    acc[m][n] = __builtin_amdgcn_mfma_f32_16x16x32_bf16(af[m], bfr[n], acc[m][n], 0, 0, 0);
        }
        __syncthreads();
    }

    const int ci = lane & 15, r4 = (lane >> 4) * 4;
#pragma unroll
    for (int m = 0; m < 4; ++m)
#pragma unroll
        for (int n = 0; n < 4; ++n) {
            const int col = wc * 64 + n * 16 + ci;
#pragma unroll
            for (int j = 0; j < 4; ++j) {
                const int row = wr * 64 + m * 16 + r4 + j;
                outp[(long)row * 128 + col] = (bf16)acc[m][n][j];
            }
        }
}

// ---------------- fusion (vectorized) ----------------
__global__ void fuse_kernel(const unsigned int* __restrict__ cm, const unsigned int* __restrict__ lat,
                            unsigned int* __restrict__ bott)
{
    const int wave = threadIdx.x >> 6;
    const int l    = threadIdx.x & 63;
    const int b    = blockIdx.x * 4 + wave;
    const unsigned int* cu = cm  + (size_t)b * 1024;
    const unsigned int* lu = lat + (size_t)b * 1024;

    float c0[16], c1[16], l0[16], l1[16];
    float sq0 = 0.f, sq1 = 0.f;
#pragma unroll
    for (int c = 0; c < 16; ++c) {
        const unsigned int vc = cu[c * 64 + l], vl = lu[c * 64 + l];
        c0[c] = __uint_as_float(vc << 16);
        c1[c] = __uint_as_float(vc & 0xffff0000u);
        l0[c] = __uint_as_float(vl << 16);
        l1[c] = __uint_as_float(vl & 0xffff0000u);
        sq0 += c0[c] * c0[c]; sq1 += c1[c] * c1[c];
    }
    const float rs0 = rsqrtf(fmaxf(sq0, 1e-12f));
    const float rs1 = rsqrtf(fmaxf(sq1, 1e-12f));
#pragma unroll
    for (int c = 0; c < 16; ++c) {
        const float cn0 = c0[c] * rs0, cn1 = c1[c] * rs1;
        float part = cn0 * l0[c] + cn1 * l1[c];
#pragma unroll
        for (int off = 32; off; off >>= 1) part += __shfl_xor(part, off);
        const float p = 1.0f / (1.0f + expf(-part));
        const float o0 = __shfl_xor(cn0, 32), o1 = __shfl_xor(cn1, 32);
        if (l < 32)
            bott[(size_t)b * 512 + c * 32 + l] =
                pack2(p * o0 + (1.f - p) * cn0, p * o1 + (1.f - p) * cn1);
    }
}

// ---------------- final: reduce z partials (bf16), relu, logits ----------------
__global__ void head2_kernel(const bf16* __restrict__ zp, const float* __restrict__ bgh,
                             const float* __restrict__ Wc, const float* __restrict__ bc,
                             float* __restrict__ out)
{
    __shared__ float zs[8][128];
    const int b0 = blockIdx.x * 8;
    const int t = threadIdx.x;
#pragma unroll
    for (int i = 0; i < 4; ++i) {
        const int idx = t + i * 256;
        const int r = idx >> 7, k = idx & 127;
        float s = bgh[k];
#pragma unroll
        for (int ks = 0; ks < 8; ++ks)
            s += (float)zp[(size_t)ks * 524288 + (size_t)(b0 + r) * 128 + k];
        zs[r][k] = fmaxf(s, 0.0f);
    }
    __syncthreads();
    if (t < 200) {
        float a[8];
#pragma unroll
        for (int r = 0; r < 8; ++r) a[r] = bc[t];
        for (int k = 0; k < 128; ++k) {
            const float wv = Wc[k * 200 + t];
#pragma unroll
            for (int r = 0; r < 8; ++r) a[r] = fmaf(zs[r][k], wv, a[r]);
        }
#pragma unroll
        for (int r = 0; r < 8; ++r) out[(size_t)(b0 + r) * 200 + t] = a[r];
    }
}

// ---------------- launch ----------------

extern "C" void kernel_launch(void* const* d_in, const int* in_sizes, int n_in,
                              void* d_out, int out_size, void* d_ws, size_t ws_size,
                              hipStream_t stream)
{
    (void)in_sizes; (void)n_in; (void)out_size; (void)ws_size;

    const float* x    = (const float*)d_in[0];
    const float* fp   = (const float*)d_in[1];
    const float* mean = (const float*)d_in[2];
    const float* Wg1  = (const float*)d_in[3];
    const float* bg1  = (const float*)d_in[4];
    const float* Wg2  = (const float*)d_in[5];
    const float* bg2  = (const float*)d_in[6];
    const float* Wf1  = (const float*)d_in[7];
    const float* bf1  = (const float*)d_in[8];
    const float* Wf2  = (const float*)d_in[9];
    const float* bf2  = (const float*)d_in[10];
    const float* Wgh  = (const float*)d_in[11];
    const float* bgh  = (const float*)d_in[12];
    const float* Wc   = (const float*)d_in[13];
    const float* bc   = (const float*)d_in[14];
    float* outp = (float*)d_out;

    char* p = (char*)d_ws;
    size_t off = 0;
    auto alloc = [&](size_t bytes) { void* r = p + off; off += (bytes + 255) & ~(size_t)255; return r; };
    bf16*  xbf    = (bf16*) alloc((size_t)4096 * 2048 * 2);
    bf16*  Wall   = (bf16*) alloc((size_t)16 * 768 * 2048 * 2);
    bf16*  Wg2T   = (bf16*) alloc((size_t)16 * 128 * 256 * 2);
    bf16*  Wf2T   = (bf16*) alloc((size_t)128 * 512 * 2);
    bf16*  WghT   = (bf16*) alloc((size_t)128 * 1024 * 2);
    float* corr_g = (float*)alloc((size_t)16 * 256 * 4);
    float* corr_f = (float*)alloc((size_t)16 * 512 * 4);
    bf16*  h      = (bf16*) alloc((size_t)16 * 4096 * 256 * 2);
    bf16*  hf     = (bf16*) alloc((size_t)16 * 4096 * 512 * 2);
    bf16*  cm     = (bf16*) alloc((size_t)4096 * 2048 * 2);
    bf16*  lat    = (bf16*) alloc((size_t)4096 * 2048 * 2);
    bf16*  bott   = (bf16*) alloc((size_t)4096 * 1024 * 2);
    bf16*  zp     = (bf16*) alloc((size_t)8 * 4096 * 128 * 2);

    // single prep launch: corr_g | corr_f | wf1 | wg1 | cvt_x | small
    prep_all<<<15232, 256, 0, stream>>>(x, xbf, fp, mean, Wg1, Wf1, Wall,
                                        corr_g, corr_f, Wg2, Wg2T, Wf2, Wf2T, Wgh, WghT);

    gemm256<<<768, 512, 0, stream>>>(xbf, Wall, bg1, corr_g, bf1, corr_f, h, hf);

    gemm_mid<<<dim3(32, 1, 32), 256, 0, stream>>>(h, hf, Wg2T, Wf2T, bg2, bf2, cm, lat);

    fuse_kernel<<<1024, 256, 0, stream>>>((const unsigned int*)cm, (const unsigned int*)lat,
                                          (unsigned int*)bott);

    gemm_zp<<<dim3(32, 1, 8), 256, 0, stream>>>(bott, WghT, zp);

    head2_kernel<<<512, 256, 0, stream>>>(zp, bgh, Wc, bc, outp);
}